// Round 4
// baseline (161.309 us; speedup 1.0000x reference)
//
#include <hip/hip_runtime.h>
#include <hip/hip_bf16.h>
#include <stdint.h>

// ---------------------------------------------------------------------------
// coAttention: out = V_i + V_t + 0.5*V_c + 0.5*V_e
// V = softmax_n( sum_k tanh(feat@W)[n,k]*wp[K+k] + bias[n] ) @ feat.
// Query half of tanh(concat([q,proj]))@wp is constant over n -> cancels in
// softmax -> q0/q1/q2 chain irrelevant. Four independent stages:
// c(N=20), e(30), i(49), t(128); B=256, D=1024, K=256.
// Row totals M=B*N: 5120, 7680, 12544, 32768; row-tiles(32) = 160/240/392/1024
// = 1816 total, 454 blocks of 4 waves (each stage's tile count %4==0).
//
// R3: A-stream-bound regime (128 FLOP per A-byte -> floor ~40us). Barrier-free
// streaming: wave owns 32x256 tile, A f32 loaded per-lane from global (once,
// coalesced), cvt to bf16 in-reg; B frags loaded dense from a frag-native
// pre-converted W layout (L2-resident). No LDS in the K-loop, no barriers ->
// HBM queue never drains (copy-ubench structure + MFMA).
// ---------------------------------------------------------------------------

#define D_DIM 1024
#define K_OUT 256

typedef float f32x4 __attribute__((ext_vector_type(4)));
typedef float f32x16 __attribute__((ext_vector_type(16)));
typedef short bf16x8 __attribute__((ext_vector_type(8)));
typedef unsigned short u16x8 __attribute__((ext_vector_type(8)));

static __device__ __forceinline__ unsigned short f2bf(float f) {
    return __builtin_bit_cast(unsigned short, __float2bfloat16(f));
}

// tanh(x) = 1 - 2/(exp(2x)+1); stable at +/-inf.
static __device__ __forceinline__ float fast_tanh(float x) {
    float e = __expf(2.0f * x);
    return 1.0f - 2.0f / (e + 1.0f);
}

// ---------------------------------------------------------------------------
// Kernel 1: W (f32 [D=1024][256]) -> wtf frag-native bf16:
// wtf[kblk][col][half][j] ; kblk=k>>4 (64), col(256), half=(k>>3)&1, j=k&7.
// ushort offset = kblk*4096 + col*16 + half*8 + j. 512KB per stage.
// B-frag for mfma_32x32x16: lane reads 8 ushorts at col=(f*32+lane&31),
// half=lane>>5 -> one dense 1KB/wave global_load_dwordx4 per frag.
// ---------------------------------------------------------------------------
__global__ __launch_bounds__(256) void convert_wt(
    const float* __restrict__ w_c, const float* __restrict__ w_e,
    const float* __restrict__ w_i, const float* __restrict__ w_t,
    unsigned short* __restrict__ wtf)
{
    const float* wsel[4] = {w_c, w_e, w_i, w_t};
    const float* W = wsel[blockIdx.x];
    unsigned short* out = wtf + (size_t)blockIdx.x * (K_OUT * D_DIM);
    const int kb = blockIdx.y;          // 0..63
    const int t = threadIdx.x;          // col 0..255

    unsigned short tmp[16];
#pragma unroll
    for (int j = 0; j < 16; ++j)
        tmp[j] = f2bf(W[(size_t)(kb * 16 + j) * K_OUT + t]);   // coalesced over t

    u16x8 lo, hi;
#pragma unroll
    for (int j = 0; j < 8; ++j) { lo[j] = tmp[j]; hi[j] = tmp[8 + j]; }
    unsigned short* dst = out + (size_t)kb * 4096 + t * 16;
    *reinterpret_cast<u16x8*>(dst) = lo;
    *reinterpret_cast<u16x8*>(dst + 8) = hi;
}

// ---------------------------------------------------------------------------
// Kernel 2: barrier-free streaming logits GEMM.
// grid 454 x 256 threads (4 waves). Wave w handles row-tile rt = bid*4+w:
// rows m0..m0+31 of its stage, all 256 cols, K=1024.
// s[m] = sum_col tanh(proj[m,col]) * wp[256+col].
// ---------------------------------------------------------------------------
__global__ __launch_bounds__(256) void logits_stream(
    const float* __restrict__ f_c, const float* __restrict__ f_e,
    const float* __restrict__ f_i, const float* __restrict__ f_t,
    const unsigned short* __restrict__ wtf,
    const float* __restrict__ wp_c, const float* __restrict__ wp_e,
    const float* __restrict__ wp_i, const float* __restrict__ wp_t,
    float* __restrict__ s_c, float* __restrict__ s_e,
    float* __restrict__ s_i, float* __restrict__ s_t)
{
    const int wv = threadIdx.x >> 6, lane = threadIdx.x & 63;
    const int rt = blockIdx.x * 4 + wv;

    const float* feat; const unsigned short* wt; const float* wp;
    float* sout; int m0;
    if (rt < 160)      { feat = f_c; wt = wtf;          wp = wp_c; sout = s_c; m0 = rt * 32; }
    else if (rt < 400) { feat = f_e; wt = wtf + 262144; wp = wp_e; sout = s_e; m0 = (rt - 160) * 32; }
    else if (rt < 792) { feat = f_i; wt = wtf + 524288; wp = wp_i; sout = s_i; m0 = (rt - 400) * 32; }
    else               { feat = f_t; wt = wtf + 786432; wp = wp_t; sout = s_t; m0 = (rt - 792) * 32; }

    const int l31 = lane & 31, lh = lane >> 5;
    // A: lane -> row m0+l31, k-offset lh*8 (+kk*16). 32B contiguous per lane.
    const float* arow = feat + (size_t)(m0 + l31) * D_DIM + lh * 8;
    // B: frag f, k-block kk: ushort off = kk*4096 + f*512 + l31*16 + lh*8.
    const unsigned short* bbase = wt + (size_t)l31 * 16 + lh * 8;

    f32x16 acc[8];
#pragma unroll
    for (int f = 0; f < 8; ++f) acc[f] = (f32x16)(0.f);

#pragma unroll 2
    for (int kk = 0; kk < 64; ++kk) {
        f32x4 a0 = *reinterpret_cast<const f32x4*>(arow + kk * 16);
        f32x4 a1 = *reinterpret_cast<const f32x4*>(arow + kk * 16 + 4);
        u16x8 bu[8];
#pragma unroll
        for (int f = 0; f < 8; ++f)
            bu[f] = *reinterpret_cast<const u16x8*>(bbase + kk * 4096 + f * 512);
        u16x8 au;
#pragma unroll
        for (int j = 0; j < 4; ++j) { au[j] = f2bf(a0[j]); au[4 + j] = f2bf(a1[j]); }
        const bf16x8 af = __builtin_bit_cast(bf16x8, au);
#pragma unroll
        for (int f = 0; f < 8; ++f)
            acc[f] = __builtin_amdgcn_mfma_f32_32x32x16_bf16(
                af, __builtin_bit_cast(bf16x8, bu[f]), acc[f], 0, 0, 0);
    }

    // epilogue: s[row] = sum_f sum over this lane's col tanh(acc)*wp2, then
    // reduce across the 32-lane col group. C/D: col=l31 (+f*32),
    // row = (r&3) + 8*(r>>2) + 4*lh.
    float wpf[8];
#pragma unroll
    for (int f = 0; f < 8; ++f) wpf[f] = wp[K_OUT + f * 32 + l31];

#pragma unroll
    for (int r = 0; r < 16; ++r) {
        float v = 0.f;
#pragma unroll
        for (int f = 0; f < 8; ++f) v += fast_tanh(acc[f][r]) * wpf[f];
        v += __shfl_xor(v, 1);
        v += __shfl_xor(v, 2);
        v += __shfl_xor(v, 4);
        v += __shfl_xor(v, 8);
        v += __shfl_xor(v, 16);
        if (l31 == 0) sout[m0 + ((r & 3) + 8 * (r >> 2) + 4 * lh)] = v;
    }
}

// ---------------------------------------------------------------------------
// Kernel 3: per (b, stage): softmax over N logits (+bias), then V = P @ feat.
// ---------------------------------------------------------------------------
struct PVStage {
    const float* s;       // [B*N]
    const float* bias;    // [N]
    const float* feat;    // [B*N][1024]
    float* v_out;         // [B][1024]
    int N;
};

__global__ __launch_bounds__(256) void softmax_pv(
    PVStage p0, PVStage p1, PVStage p2, PVStage p3)
{
    PVStage st = (blockIdx.y == 0) ? p0 : (blockIdx.y == 1) ? p1
               : (blockIdx.y == 2) ? p2 : p3;
    const int b = blockIdx.x, t = threadIdx.x;
    const int N = st.N;

    __shared__ float P[128];
    __shared__ float inv_s;

    if (t < N) P[t] = st.s[b * N + t] + st.bias[t];
    __syncthreads();
    if (t < 64) {
        float m = -3.4e38f;
        for (int n = t; n < N; n += 64) m = fmaxf(m, P[n]);
#pragma unroll
        for (int sh = 32; sh; sh >>= 1) m = fmaxf(m, __shfl_xor(m, sh));
        float ssum = 0.f;
        for (int n = t; n < N; n += 64) { float e = __expf(P[n] - m); P[n] = e; ssum += e; }
#pragma unroll
        for (int sh = 32; sh; sh >>= 1) ssum += __shfl_xor(ssum, sh);
        if (t == 0) inv_s = 1.0f / ssum;
    }
    __syncthreads();
    const float inv = inv_s;

    f32x4 accv = (f32x4){0.f, 0.f, 0.f, 0.f};
    const float* fb = st.feat + (size_t)b * N * D_DIM + t * 4;
    for (int n = 0; n < N; ++n) {
        f32x4 f = *reinterpret_cast<const f32x4*>(fb + (size_t)n * D_DIM);
        accv += (P[n] * inv) * f;
    }
    *reinterpret_cast<f32x4*>(&st.v_out[(size_t)b * D_DIM + t * 4]) = accv;
}

// ---------------------------------------------------------------------------
// Kernel 4: out = V_i + V_t + 0.5*V_c + 0.5*V_e
// ---------------------------------------------------------------------------
__global__ __launch_bounds__(256) void combine_out(
    const float* __restrict__ vc, const float* __restrict__ ve,
    const float* __restrict__ vi, const float* __restrict__ vt,
    float* __restrict__ out)
{
    const int i = (blockIdx.x * 256 + threadIdx.x) * 4;
    f32x4 a = *reinterpret_cast<const f32x4*>(vi + i);
    f32x4 bb = *reinterpret_cast<const f32x4*>(vt + i);
    f32x4 c = *reinterpret_cast<const f32x4*>(vc + i);
    f32x4 e = *reinterpret_cast<const f32x4*>(ve + i);
    *reinterpret_cast<f32x4*>(out + i) = a + bb + 0.5f * c + 0.5f * e;
}

// ---------------------------------------------------------------------------
extern "C" void kernel_launch(void* const* d_in, const int* in_sizes, int n_in,
                              void* d_out, int out_size, void* d_ws, size_t ws_size,
                              hipStream_t stream)
{
    const float* ifeature = (const float*)d_in[0];   // (256,49,1024)
    const float* tfeature = (const float*)d_in[1];   // (256,128,1024)
    const float* cfeature = (const float*)d_in[2];   // (256,20,1024)
    const float* efeature = (const float*)d_in[3];   // (256,30,1024)
    const float* w_Vc = (const float*)d_in[5];
    const float* w_Pc = (const float*)d_in[6];
    const float* b_Pc = (const float*)d_in[7];
    const float* w_Ve = (const float*)d_in[8];
    const float* w_Pe = (const float*)d_in[9];
    const float* b_Pe = (const float*)d_in[10];
    const float* w_Vi = (const float*)d_in[11];
    const float* w_Pi = (const float*)d_in[13];
    const float* b_Pi = (const float*)d_in[14];
    const float* w_Vt = (const float*)d_in[16];
    const float* w_Pt = (const float*)d_in[17];
    const float* b_Pt = (const float*)d_in[18];

    // workspace layout (~7 MB)
    char* ws = (char*)d_ws;
    unsigned short* wtf = (unsigned short*)ws;                // 4 x 512KB bf16
    float* s_c = (float*)(ws + 2u * 1024 * 1024);             // 5120
    float* s_e = s_c + 5120;                                  // 7680
    float* s_i = s_e + 7680;                                  // 12544
    float* s_t = s_i + 12544;                                 // 32768
    float* v_c = (float*)(ws + 3u * 1024 * 1024);             // 4 x 1MB
    float* v_e = v_c + 256 * 1024;
    float* v_i = v_e + 256 * 1024;
    float* v_t = v_i + 256 * 1024;

    convert_wt<<<dim3(4, 64), 256, 0, stream>>>(w_Vc, w_Ve, w_Vi, w_Vt, wtf);

    logits_stream<<<454, 256, 0, stream>>>(
        cfeature, efeature, ifeature, tfeature, wtf,
        w_Pc, w_Pe, w_Pi, w_Pt, s_c, s_e, s_i, s_t);

    PVStage p0{s_c, b_Pc, cfeature, v_c, 20};
    PVStage p1{s_e, b_Pe, efeature, v_e, 30};
    PVStage p2{s_i, b_Pi, ifeature, v_i, 49};
    PVStage p3{s_t, b_Pt, tfeature, v_t, 128};
    softmax_pv<<<dim3(256, 4), 256, 0, stream>>>(p0, p1, p2, p3);

    combine_out<<<256, 256, 0, stream>>>(v_c, v_e, v_i, v_t, (float*)d_out);
}

// Round 5
// 99.381 us; speedup vs baseline: 1.6231x; 1.6231x over previous
//
#include <hip/hip_runtime.h>
#include <hip/hip_bf16.h>
#include <stdint.h>

// ---------------------------------------------------------------------------
// coAttention: out = V_i + V_t + 0.5*V_c + 0.5*V_e
// V = softmax_n( sum_k tanh(feat@W)[n,k]*wp[K+k] + bias[n] ) @ feat.
// Query half of tanh(concat([q,proj]))@wp is constant over n -> cancels in
// softmax -> q0/q1/q2 chain irrelevant. Four independent stages:
// c(N=20), e(30), i(49), t(128); B=256, D=1024, K=256.
// M = B*N: 5120, 7680, 12544, 32768 -> 64-row tiles: 80/120/196/512 = 908.
//
// R4: residency fix. BM=64 (908 blocks of 4 waves) -> ~3.5 blocks/CU vs
// R0's 1.77 (the m114 overlap mechanism needs >=3). A-tile only in LDS
// (bf16, XOR-swizzled, double-buffered, ONE barrier/iter); W read as
// frag-native bf16 straight from L2 (R3-proven path, no W staging).
// Per iter: barrier -> B loads first, then A prefetch (so B's vmcnt wait
// leaves A in flight) -> ds_read+MFMA -> cvt+ds_write other buffer.
// ---------------------------------------------------------------------------

#define D_DIM 1024
#define K_OUT 256
#define BM 64
#define BK 64
#define NT 16   // K-tiles = 1024/64

typedef float f32x4 __attribute__((ext_vector_type(4)));
typedef short bf16x8 __attribute__((ext_vector_type(8)));
typedef unsigned short u16x8 __attribute__((ext_vector_type(8)));

static __device__ __forceinline__ unsigned short f2bf(float f) {
    return __builtin_bit_cast(unsigned short, __float2bfloat16(f));
}

// tanh(x) = 1 - 2/(exp(2x)+1); stable at +/-inf.
static __device__ __forceinline__ float fast_tanh(float x) {
    float e = __expf(2.0f * x);
    return 1.0f - 2.0f / (e + 1.0f);
}

// ---------------------------------------------------------------------------
// Kernel 1: W (f32 [1024][256]) -> frag-native bf16:
// ushort off = kblk*4096 + col*16 + half*8 + j, where k = kblk*16+half*8+j.
// ---------------------------------------------------------------------------
__global__ __launch_bounds__(256) void convert_wt(
    const float* __restrict__ w_c, const float* __restrict__ w_e,
    const float* __restrict__ w_i, const float* __restrict__ w_t,
    unsigned short* __restrict__ wtf)
{
    const float* wsel[4] = {w_c, w_e, w_i, w_t};
    const float* W = wsel[blockIdx.x];
    unsigned short* out = wtf + (size_t)blockIdx.x * (K_OUT * D_DIM);
    const int kb = blockIdx.y;          // 0..63
    const int t = threadIdx.x;          // col 0..255

    unsigned short tmp[16];
#pragma unroll
    for (int j = 0; j < 16; ++j)
        tmp[j] = f2bf(W[(size_t)(kb * 16 + j) * K_OUT + t]);   // coalesced over t

    u16x8 lo, hi;
#pragma unroll
    for (int j = 0; j < 8; ++j) { lo[j] = tmp[j]; hi[j] = tmp[8 + j]; }
    unsigned short* dst = out + (size_t)kb * 4096 + t * 16;
    *reinterpret_cast<u16x8*>(dst) = lo;
    *reinterpret_cast<u16x8*>(dst + 8) = hi;
}

// ---------------------------------------------------------------------------
// Kernel 2: fused logits GEMM, BM=64 x 256 cols, BK=64.
// 256 threads = 4 waves; wave wv owns cols wv*64..+63 (rows shared).
// s[m] = sum_col tanh(proj[m,col]) * wp[256+col].
// ---------------------------------------------------------------------------
struct GemmStage {
    const float* feat;          // [M][1024] f32
    const unsigned short* wt;   // frag-native bf16, 256K ushorts
    const float* wp;            // [512] f32 (use [256..])
    float* s_out;               // [M]
    int blk_start;              // in 64-row tiles
};

__global__ __launch_bounds__(256, 3) void logits_gemm(
    GemmStage g0, GemmStage g1, GemmStage g2, GemmStage g3)
{
    __shared__ __align__(16) unsigned char As[2][BM * 128];  // 2 x 8 KB bf16
    __shared__ float partial[BM][4];

    const int bid = blockIdx.x;
    GemmStage st;
    if (bid < g1.blk_start) st = g0;
    else if (bid < g2.blk_start) st = g1;
    else if (bid < g3.blk_start) st = g2;
    else st = g3;
    const int m0 = (bid - st.blk_start) * BM;

    const int t = threadIdx.x;
    // staging: thread -> (row r, quarter qd) ; 16 f32 per thread
    const int r = t >> 2, qd = t & 3;
    // wave/frag coords
    const int wv = t >> 6, lane = t & 63;
    const int q = lane >> 4, c16 = lane & 15;

    const float* aptr = st.feat + (size_t)(m0 + r) * D_DIM + qd * 16;
    const int wo0 = r * 128 + (((qd * 2    ) ^ (r & 7)) << 4);
    const int wo1 = r * 128 + (((qd * 2 + 1) ^ (r & 7)) << 4);
    // B frag base (ushort index): k = kt*64 + ks*32 + q*8 + j
    const unsigned short* bb = st.wt + (q >> 1) * 4096
                             + ((wv * 64 + c16) << 4) + (q & 1) * 8;
    // A-frag chunk xor, uniform over mt (mt*16 % 8 == 0)
    const int ck0 = ((0 * 4 + q) ^ (c16 & 7)) << 4;
    const int ck1 = ((1 * 4 + q) ^ (c16 & 7)) << 4;

    float wpf[4];
#pragma unroll
    for (int nt = 0; nt < 4; ++nt) wpf[nt] = st.wp[K_OUT + wv * 64 + nt * 16 + c16];

    f32x4 acc[4][4];
#pragma unroll
    for (int i = 0; i < 4; ++i)
#pragma unroll
        for (int j = 0; j < 4; ++j) acc[i][j] = (f32x4){0.f, 0.f, 0.f, 0.f};

    f32x4 pa[4];
    // prologue: tile 0 -> As[0]
#pragma unroll
    for (int j = 0; j < 4; ++j)
        pa[j] = *reinterpret_cast<const f32x4*>(aptr + j * 4);
    {
        u16x8 o0, o1;
#pragma unroll
        for (int j = 0; j < 4; ++j) {
            o0[j] = f2bf(pa[0][j]); o0[4 + j] = f2bf(pa[1][j]);
            o1[j] = f2bf(pa[2][j]); o1[4 + j] = f2bf(pa[3][j]);
        }
        *reinterpret_cast<u16x8*>(&As[0][wo0]) = o0;
        *reinterpret_cast<u16x8*>(&As[0][wo1]) = o1;
    }

#pragma unroll 1
    for (int kt = 0; kt < NT; ++kt) {
        __syncthreads();   // As[kt&1] writes visible; prev reads of As[(kt+1)&1] done
        // ---- B loads FIRST (L2), so their wait leaves A prefetch in flight ----
        u16x8 bfr[2][4];
        const unsigned short* bk = bb + kt * 16384;
#pragma unroll
        for (int ks = 0; ks < 2; ++ks)
#pragma unroll
            for (int nt = 0; nt < 4; ++nt)
                bfr[ks][nt] = *reinterpret_cast<const u16x8*>(bk + ks * 8192 + nt * 256);
        // ---- A prefetch for next tile (wraps harmlessly at kt=15) ----
        const int ktn = (kt + 1) & 15;
#pragma unroll
        for (int j = 0; j < 4; ++j)
            pa[j] = *reinterpret_cast<const f32x4*>(aptr + ktn * 64 + j * 4);
        // ---- compute from As[kt&1] ----
        const unsigned char* buf = As[kt & 1];
#pragma unroll
        for (int ks = 0; ks < 2; ++ks) {
            const int ck = ks ? ck1 : ck0;
            bf16x8 af[4];
#pragma unroll
            for (int mt = 0; mt < 4; ++mt)
                af[mt] = *reinterpret_cast<const bf16x8*>(&buf[(mt * 16 + c16) * 128 + ck]);
#pragma unroll
            for (int mt = 0; mt < 4; ++mt)
#pragma unroll
                for (int nt = 0; nt < 4; ++nt)
                    acc[mt][nt] = __builtin_amdgcn_mfma_f32_16x16x32_bf16(
                        af[mt], __builtin_bit_cast(bf16x8, bfr[ks][nt]),
                        acc[mt][nt], 0, 0, 0);
        }
        // ---- convert + write next tile into the other buffer ----
        if (kt + 1 < NT) {
            u16x8 o0, o1;
#pragma unroll
            for (int j = 0; j < 4; ++j) {
                o0[j] = f2bf(pa[0][j]); o0[4 + j] = f2bf(pa[1][j]);
                o1[j] = f2bf(pa[2][j]); o1[4 + j] = f2bf(pa[3][j]);
            }
            unsigned char* nbuf = As[(kt + 1) & 1];
            *reinterpret_cast<u16x8*>(&nbuf[wo0]) = o0;
            *reinterpret_cast<u16x8*>(&nbuf[wo1]) = o1;
        }
    }

    // ---- epilogue: tanh * wp2, reduce cols -> s_out ----
    // C/D 16x16: col = c16 (+wv*64+nt*16), row = q*4 + reg (+mt*16)
#pragma unroll
    for (int mt = 0; mt < 4; ++mt) {
#pragma unroll
        for (int rg = 0; rg < 4; ++rg) {
            float v = 0.f;
#pragma unroll
            for (int nt = 0; nt < 4; ++nt)
                v += fast_tanh(acc[mt][nt][rg]) * wpf[nt];
            v += __shfl_xor(v, 1);
            v += __shfl_xor(v, 2);
            v += __shfl_xor(v, 4);
            v += __shfl_xor(v, 8);
            if (c16 == 0) partial[mt * 16 + q * 4 + rg][wv] = v;
        }
    }
    __syncthreads();
    if (t < BM)
        st.s_out[m0 + t] = partial[t][0] + partial[t][1] + partial[t][2] + partial[t][3];
}

// ---------------------------------------------------------------------------
// Kernel 3: per (b, stage): softmax over N logits (+bias), then V = P @ feat.
// ---------------------------------------------------------------------------
struct PVStage {
    const float* s;       // [B*N]
    const float* bias;    // [N]
    const float* feat;    // [B*N][1024]
    float* v_out;         // [B][1024]
    int N;
};

__global__ __launch_bounds__(256) void softmax_pv(
    PVStage p0, PVStage p1, PVStage p2, PVStage p3)
{
    PVStage st = (blockIdx.y == 0) ? p0 : (blockIdx.y == 1) ? p1
               : (blockIdx.y == 2) ? p2 : p3;
    const int b = blockIdx.x, t = threadIdx.x;
    const int N = st.N;

    __shared__ float P[128];
    __shared__ float inv_s;

    if (t < N) P[t] = st.s[b * N + t] + st.bias[t];
    __syncthreads();
    if (t < 64) {
        float m = -3.4e38f;
        for (int n = t; n < N; n += 64) m = fmaxf(m, P[n]);
#pragma unroll
        for (int sh = 32; sh; sh >>= 1) m = fmaxf(m, __shfl_xor(m, sh));
        float ssum = 0.f;
        for (int n = t; n < N; n += 64) { float e = __expf(P[n] - m); P[n] = e; ssum += e; }
#pragma unroll
        for (int sh = 32; sh; sh >>= 1) ssum += __shfl_xor(ssum, sh);
        if (t == 0) inv_s = 1.0f / ssum;
    }
    __syncthreads();
    const float inv = inv_s;

    f32x4 accv = (f32x4){0.f, 0.f, 0.f, 0.f};
    const float* fb = st.feat + (size_t)b * N * D_DIM + t * 4;
    for (int n = 0; n < N; ++n) {
        f32x4 f = *reinterpret_cast<const f32x4*>(fb + (size_t)n * D_DIM);
        accv += (P[n] * inv) * f;
    }
    *reinterpret_cast<f32x4*>(&st.v_out[(size_t)b * D_DIM + t * 4]) = accv;
}

// ---------------------------------------------------------------------------
// Kernel 4: out = V_i + V_t + 0.5*V_c + 0.5*V_e
// ---------------------------------------------------------------------------
__global__ __launch_bounds__(256) void combine_out(
    const float* __restrict__ vc, const float* __restrict__ ve,
    const float* __restrict__ vi, const float* __restrict__ vt,
    float* __restrict__ out)
{
    const int i = (blockIdx.x * 256 + threadIdx.x) * 4;
    f32x4 a = *reinterpret_cast<const f32x4*>(vi + i);
    f32x4 bb = *reinterpret_cast<const f32x4*>(vt + i);
    f32x4 c = *reinterpret_cast<const f32x4*>(vc + i);
    f32x4 e = *reinterpret_cast<const f32x4*>(ve + i);
    *reinterpret_cast<f32x4*>(out + i) = a + bb + 0.5f * c + 0.5f * e;
}

// ---------------------------------------------------------------------------
extern "C" void kernel_launch(void* const* d_in, const int* in_sizes, int n_in,
                              void* d_out, int out_size, void* d_ws, size_t ws_size,
                              hipStream_t stream)
{
    const float* ifeature = (const float*)d_in[0];   // (256,49,1024)
    const float* tfeature = (const float*)d_in[1];   // (256,128,1024)
    const float* cfeature = (const float*)d_in[2];   // (256,20,1024)
    const float* efeature = (const float*)d_in[3];   // (256,30,1024)
    const float* w_Vc = (const float*)d_in[5];
    const float* w_Pc = (const float*)d_in[6];
    const float* b_Pc = (const float*)d_in[7];
    const float* w_Ve = (const float*)d_in[8];
    const float* w_Pe = (const float*)d_in[9];
    const float* b_Pe = (const float*)d_in[10];
    const float* w_Vi = (const float*)d_in[11];
    const float* w_Pi = (const float*)d_in[13];
    const float* b_Pi = (const float*)d_in[14];
    const float* w_Vt = (const float*)d_in[16];
    const float* w_Pt = (const float*)d_in[17];
    const float* b_Pt = (const float*)d_in[18];

    // workspace layout (~7 MB)
    char* ws = (char*)d_ws;
    unsigned short* wtf = (unsigned short*)ws;                // 4 x 512KB bf16
    float* s_c = (float*)(ws + 2u * 1024 * 1024);             // 5120
    float* s_e = s_c + 5120;                                  // 7680
    float* s_i = s_e + 7680;                                  // 12544
    float* s_t = s_i + 12544;                                 // 32768
    float* v_c = (float*)(ws + 3u * 1024 * 1024);             // 4 x 1MB
    float* v_e = v_c + 256 * 1024;
    float* v_i = v_e + 256 * 1024;
    float* v_t = v_i + 256 * 1024;

    convert_wt<<<dim3(4, 64), 256, 0, stream>>>(w_Vc, w_Ve, w_Vi, w_Vt, wtf);

    // 64-row tiles: c=80, e=120, i=196, t=512 -> 908 blocks
    GemmStage g0{cfeature, wtf,          w_Pc, s_c, 0};
    GemmStage g1{efeature, wtf + 262144, w_Pe, s_e, 80};
    GemmStage g2{ifeature, wtf + 524288, w_Pi, s_i, 200};
    GemmStage g3{tfeature, wtf + 786432, w_Pt, s_t, 396};
    logits_gemm<<<908, 256, 0, stream>>>(g0, g1, g2, g3);

    PVStage p0{s_c, b_Pc, cfeature, v_c, 20};
    PVStage p1{s_e, b_Pe, efeature, v_e, 30};
    PVStage p2{s_i, b_Pi, ifeature, v_i, 49};
    PVStage p3{s_t, b_Pt, tfeature, v_t, 128};
    softmax_pv<<<dim3(256, 4), 256, 0, stream>>>(p0, p1, p2, p3);

    combine_out<<<256, 256, 0, stream>>>(v_c, v_e, v_i, v_t, (float*)d_out);
}